// Round 1
// baseline (32882.382 us; speedup 1.0000x reference)
//
#include <hip/hip_runtime.h>
#include <hip/hip_bf16.h>
#include <math.h>

typedef __bf16 bf16;
typedef __bf16 bf16x8 __attribute__((ext_vector_type(8)));
typedef float f32x16 __attribute__((ext_vector_type(16)));

#define T_STEPS 512
#define BATCH   128
#define DIN     512
#define HID     1024
#define G4      4096
#define DOUT    512

__device__ __forceinline__ float sigm(float x){ return 1.0f / (1.0f + __expf(-x)); }

// ---------------- prep kernels ----------------

__global__ void split_kernel(const float* __restrict__ src, bf16* __restrict__ hi,
                             bf16* __restrict__ lo, int n){
    int i = blockIdx.x * blockDim.x + threadIdx.x;
    if (i < n){
        float v = src[i];
        bf16 h = (bf16)v;
        hi[i] = h;
        lo[i] = (bf16)(v - (float)h);
    }
}

// x: [B][T][D] fp32  ->  xhi/xlo: [T][B][D] bf16
__global__ void xsplit_kernel(const float* __restrict__ x, bf16* __restrict__ xhi,
                              bf16* __restrict__ xlo){
    int i = blockIdx.x * blockDim.x + threadIdx.x;   // < T*B*D = 2^25
    int d  = i & (DIN - 1);
    int tb = i >> 9;            // DIN = 512
    int b  = tb & (BATCH - 1);
    int t  = tb >> 7;           // BATCH = 128
    float v = x[((size_t)b * T_STEPS + t) * DIN + d];
    bf16 h = (bf16)v;
    xhi[i] = h;
    xlo[i] = (bf16)(v - (float)h);
}

__global__ void bias_kernel(const float* __restrict__ bih1, const float* __restrict__ bhh1,
                            const float* __restrict__ bih2, const float* __restrict__ bhh2,
                            float* __restrict__ bias1, float* __restrict__ bias2){
    int i = blockIdx.x * blockDim.x + threadIdx.x;
    if (i < G4){
        bias1[i] = bih1[i] + bhh1[i];
        bias2[i] = bih2[i] + bhh2[i];
    }
}

// ---------------- per-step GEMM (both layers, pipelined) ----------------
// grid = 256 blocks, 256 threads (4 waves). Block tile: 128 rows x 64 cols.
// blocks [0,128): layer1 at time t      (shard0: x-part K=512, shard1: h1-part K=1024)
// blocks [128,256): layer2 at time t-1  (shard0: h1-part K=1024, shard1: h2-part K=1024)
// 3-term bf16 split accumulation into fp32 partials gpart[layer][shard][128][4096].
__global__ __launch_bounds__(256)
void gemm_step(const bf16* __restrict__ xhi,  const bf16* __restrict__ xlo,
               const bf16* __restrict__ wih1h, const bf16* __restrict__ wih1l,
               const bf16* __restrict__ whh1h, const bf16* __restrict__ whh1l,
               const bf16* __restrict__ wih2h, const bf16* __restrict__ wih2l,
               const bf16* __restrict__ whh2h, const bf16* __restrict__ whh2l,
               const bf16* __restrict__ h1hi,  const bf16* __restrict__ h1lo,   // [2][128][1024]
               const bf16* __restrict__ h2hi,  const bf16* __restrict__ h2lo,   // [2][128][1024]
               float* __restrict__ gpart, int t)
{
    int bid   = blockIdx.x;
    int layer = bid >> 7;
    if (layer == 0 && t == T_STEPS) return;   // last round: layer2 only
    if (layer == 1 && t == 0)       return;   // first round: layer1 only
    int within = bid & 127;
    int shard  = within >> 6;
    int ntile  = within & 63;

    int lane = threadIdx.x & 63;
    int wave = threadIdx.x >> 6;
    int row_base = (wave >> 1) * 64;                 // 0 or 64
    int col_base = ntile * 64 + (wave & 1) * 32;     // global gates column

    const bf16 *A_hi, *A_lo, *B_hi, *B_lo;
    int K;
    if (layer == 0){
        if (shard == 0){
            A_hi = xhi + (size_t)t * BATCH * DIN;  A_lo = xlo + (size_t)t * BATCH * DIN;
            K = DIN;  B_hi = wih1h; B_lo = wih1l;
        } else {
            int p = (t - 1) & 1;
            A_hi = h1hi + (size_t)p * BATCH * HID; A_lo = h1lo + (size_t)p * BATCH * HID;
            K = HID;  B_hi = whh1h; B_lo = whh1l;
        }
    } else {
        // layer2 computes time s = t-1: needs h1(s) [parity (t-1)&1], h2(s-1) [parity t&1]
        if (shard == 0){
            int p = (t - 1) & 1;
            A_hi = h1hi + (size_t)p * BATCH * HID; A_lo = h1lo + (size_t)p * BATCH * HID;
            K = HID;  B_hi = wih2h; B_lo = wih2l;
        } else {
            int p = t & 1;
            A_hi = h2hi + (size_t)p * BATCH * HID; A_lo = h2lo + (size_t)p * BATCH * HID;
            K = HID;  B_hi = whh2h; B_lo = whh2l;
        }
    }

    // mfma_f32_32x32x16_bf16 fragment addressing:
    //   A: lane l -> row = l&31 (+32 for second M-frag), k = 8*(l>>5) + [0..7]
    //   B: lane l -> col = l&31, same k pattern (W stored [4096][K] row-major = B^T)
    int arow0 = row_base + (lane & 31);
    int bcol  = col_base + (lane & 31);
    int khalf = 8 * (lane >> 5);

    const bf16* pa0h = A_hi + (size_t)arow0 * K + khalf;
    const bf16* pa0l = A_lo + (size_t)arow0 * K + khalf;
    const bf16* pa1h = pa0h + (size_t)32 * K;
    const bf16* pa1l = pa0l + (size_t)32 * K;
    const bf16* pbh  = B_hi + (size_t)bcol * K + khalf;
    const bf16* pbl  = B_lo + (size_t)bcol * K + khalf;

    f32x16 acc0 = {0,0,0,0,0,0,0,0,0,0,0,0,0,0,0,0};
    f32x16 acc1 = {0,0,0,0,0,0,0,0,0,0,0,0,0,0,0,0};

    #pragma unroll 4
    for (int k = 0; k < K; k += 16){
        bf16x8 a0h = *(const bf16x8*)(pa0h + k);
        bf16x8 a1h = *(const bf16x8*)(pa1h + k);
        bf16x8 a0l = *(const bf16x8*)(pa0l + k);
        bf16x8 a1l = *(const bf16x8*)(pa1l + k);
        bf16x8 bh  = *(const bf16x8*)(pbh  + k);
        bf16x8 bl  = *(const bf16x8*)(pbl  + k);
        // w_hi*h_hi + w_lo*h_hi + w_hi*h_lo
        acc0 = __builtin_amdgcn_mfma_f32_32x32x16_bf16(a0h, bh, acc0, 0, 0, 0);
        acc1 = __builtin_amdgcn_mfma_f32_32x32x16_bf16(a1h, bh, acc1, 0, 0, 0);
        acc0 = __builtin_amdgcn_mfma_f32_32x32x16_bf16(a0h, bl, acc0, 0, 0, 0);
        acc1 = __builtin_amdgcn_mfma_f32_32x32x16_bf16(a1h, bl, acc1, 0, 0, 0);
        acc0 = __builtin_amdgcn_mfma_f32_32x32x16_bf16(a0l, bh, acc0, 0, 0, 0);
        acc1 = __builtin_amdgcn_mfma_f32_32x32x16_bf16(a1l, bh, acc1, 0, 0, 0);
    }

    // C/D layout: col = lane&31, row = (r&3) + 8*(r>>2) + 4*(lane>>5)
    float* gp = gpart + ((size_t)layer * 2 + shard) * BATCH * G4;
    #pragma unroll
    for (int r = 0; r < 16; ++r){
        int row = row_base + (r & 3) + 8 * (r >> 2) + 4 * (lane >> 5);
        gp[(size_t)row * G4 + bcol]        = acc0[r];
        gp[(size_t)(row + 32) * G4 + bcol] = acc1[r];
    }
}

// ---------------- per-step cell update (both layers) ----------------
__global__ __launch_bounds__(256)
void cell_step(const float* __restrict__ gpart,
               const float* __restrict__ bias1, const float* __restrict__ bias2,
               float* __restrict__ c1, float* __restrict__ c2,
               bf16* __restrict__ h1hi, bf16* __restrict__ h1lo,
               bf16* __restrict__ h2hi, bf16* __restrict__ h2lo,
               float* __restrict__ h2t, int t)
{
    int tid = blockIdx.x * blockDim.x + threadIdx.x;   // 128*256 = 32768 threads
    for (int L = 0; L < 2; ++L){
        if (L == 0 && t == T_STEPS) continue;
        if (L == 1 && t == 0)       continue;
        int s = (L == 0) ? t : (t - 1);
        const float* gp0  = gpart + ((size_t)L * 2 + 0) * BATCH * G4;
        const float* gp1  = gpart + ((size_t)L * 2 + 1) * BATCH * G4;
        const float* bias = (L == 0) ? bias1 : bias2;
        float*       c    = (L == 0) ? c1 : c2;
        int par = s & 1;
        bf16* hhi = ((L == 0) ? h1hi : h2hi) + (size_t)par * BATCH * HID;
        bf16* hlo = ((L == 0) ? h1lo : h2lo) + (size_t)par * BATCH * HID;
        for (int it = tid; it < BATCH * HID; it += 32768){
            int b = it >> 10;
            int j = it & (HID - 1);
            size_t base = (size_t)b * G4 + j;
            float gi = bias[j]        + gp0[base]        + gp1[base];
            float gf = bias[j + 1024] + gp0[base + 1024] + gp1[base + 1024];
            float gg = bias[j + 2048] + gp0[base + 2048] + gp1[base + 2048];
            float go = bias[j + 3072] + gp0[base + 3072] + gp1[base + 3072];
            float iv = sigm(gi), fv = sigm(gf), gv = tanhf(gg), ov = sigm(go);
            float cn = fv * c[it] + iv * gv;
            c[it] = cn;
            float h = ov * tanhf(cn);
            bf16 hh = (bf16)h;
            hhi[it] = hh;
            hlo[it] = (bf16)(h - (float)hh);
            if (L == 1 && s == T_STEPS - 1) h2t[(size_t)j * BATCH + b] = h;  // transposed fp32 for out-proj
        }
    }
}

// ---------------- output projection (fp32, one-time) ----------------
__global__ __launch_bounds__(128)
void outproj(const float* __restrict__ h2t, const float* __restrict__ wout,
             const float* __restrict__ bout, float* __restrict__ out){
    int o = blockIdx.x;      // 512 blocks
    int b = threadIdx.x;     // 128 threads
    float acc = bout[o];
    const float* wr = wout + (size_t)o * HID;
    for (int k = 0; k < HID; ++k)
        acc += wr[k] * h2t[(size_t)k * BATCH + b];
    out[(size_t)b * DOUT + o] = acc;
}

// ---------------- host launch ----------------
extern "C" void kernel_launch(void* const* d_in, const int* in_sizes, int n_in,
                              void* d_out, int out_size, void* d_ws, size_t ws_size,
                              hipStream_t stream)
{
    const float* x    = (const float*)d_in[0];
    const float* wih1 = (const float*)d_in[1];
    const float* whh1 = (const float*)d_in[2];
    const float* bih1 = (const float*)d_in[3];
    const float* bhh1 = (const float*)d_in[4];
    const float* wih2 = (const float*)d_in[5];
    const float* whh2 = (const float*)d_in[6];
    const float* bih2 = (const float*)d_in[7];
    const float* bhh2 = (const float*)d_in[8];
    const float* wout = (const float*)d_in[9];
    const float* bout = (const float*)d_in[10];
    float* out = (float*)d_out;

    char* p = (char*)d_ws;
    auto alloc = [&](size_t bytes) -> char* {
        char* r = p;
        p += (bytes + 255) & ~(size_t)255;
        return r;
    };

    bf16* xhi   = (bf16*)alloc((size_t)T_STEPS * BATCH * DIN * 2);
    bf16* xlo   = (bf16*)alloc((size_t)T_STEPS * BATCH * DIN * 2);
    bf16* wih1h = (bf16*)alloc((size_t)G4 * DIN * 2);
    bf16* wih1l = (bf16*)alloc((size_t)G4 * DIN * 2);
    bf16* whh1h = (bf16*)alloc((size_t)G4 * HID * 2);
    bf16* whh1l = (bf16*)alloc((size_t)G4 * HID * 2);
    bf16* wih2h = (bf16*)alloc((size_t)G4 * HID * 2);
    bf16* wih2l = (bf16*)alloc((size_t)G4 * HID * 2);
    bf16* whh2h = (bf16*)alloc((size_t)G4 * HID * 2);
    bf16* whh2l = (bf16*)alloc((size_t)G4 * HID * 2);
    float* bias1 = (float*)alloc(G4 * 4);
    float* bias2 = (float*)alloc(G4 * 4);
    // state block (zeroed contiguously): h1hi[2],h1lo[2],h2hi[2],h2lo[2],c1,c2
    char* zbase = p;
    bf16* h1hi = (bf16*)alloc((size_t)2 * BATCH * HID * 2);
    bf16* h1lo = (bf16*)alloc((size_t)2 * BATCH * HID * 2);
    bf16* h2hi = (bf16*)alloc((size_t)2 * BATCH * HID * 2);
    bf16* h2lo = (bf16*)alloc((size_t)2 * BATCH * HID * 2);
    float* c1  = (float*)alloc((size_t)BATCH * HID * 4);
    float* c2  = (float*)alloc((size_t)BATCH * HID * 4);
    size_t zbytes = (size_t)(p - zbase);
    float* gpart = (float*)alloc((size_t)2 * 2 * BATCH * G4 * 4);
    float* h2t   = (float*)alloc((size_t)HID * BATCH * 4);
    (void)ws_size; (void)in_sizes; (void)n_in; (void)out_size;

    // prep: split weights / x, sum biases, zero states
    split_kernel<<<(G4 * DIN + 255) / 256, 256, 0, stream>>>(wih1, wih1h, wih1l, G4 * DIN);
    split_kernel<<<(G4 * HID + 255) / 256, 256, 0, stream>>>(whh1, whh1h, whh1l, G4 * HID);
    split_kernel<<<(G4 * HID + 255) / 256, 256, 0, stream>>>(wih2, wih2h, wih2l, G4 * HID);
    split_kernel<<<(G4 * HID + 255) / 256, 256, 0, stream>>>(whh2, whh2h, whh2l, G4 * HID);
    bias_kernel<<<(G4 + 255) / 256, 256, 0, stream>>>(bih1, bhh1, bih2, bhh2, bias1, bias2);
    xsplit_kernel<<<(T_STEPS * BATCH * DIN) / 256, 256, 0, stream>>>(x, xhi, xlo);
    hipMemsetAsync(zbase, 0, zbytes, stream);

    // 513 pipelined rounds: round t does layer1(t) and layer2(t-1)
    for (int t = 0; t <= T_STEPS; ++t){
        gemm_step<<<256, 256, 0, stream>>>(xhi, xlo, wih1h, wih1l, whh1h, whh1l,
                                           wih2h, wih2l, whh2h, whh2l,
                                           h1hi, h1lo, h2hi, h2lo, gpart, t);
        cell_step<<<128, 256, 0, stream>>>(gpart, bias1, bias2, c1, c2,
                                           h1hi, h1lo, h2hi, h2lo, h2t, t);
    }

    outproj<<<DOUT, BATCH, 0, stream>>>(h2t, wout, bout, out);
}

// Round 3
// 11809.921 us; speedup vs baseline: 2.7843x; 2.7843x over previous
//
#include <hip/hip_runtime.h>
#include <hip/hip_bf16.h>
#include <math.h>

typedef __bf16 bf16;
typedef __bf16 bf16x8 __attribute__((ext_vector_type(8)));
typedef float f32x16 __attribute__((ext_vector_type(16)));

#define T_STEPS 512
#define BATCH   128
#define DIN     512
#define HID     1024
#define G4      4096
#define DOUT    512

__device__ __forceinline__ float sigm(float x){ return 1.0f / (1.0f + __expf(-x)); }

// Staged "A" layout within one K-step (32 k) of a [128 x K] activation matrix:
// [kstep][ks2=2][mf=4][kg=2][row=32][8elems]  (4096 elems per kstep)
__device__ __forceinline__ int zoff(int b, int k){
    return (k >> 5) * 4096 + ((k >> 4) & 1) * 2048 + (b >> 5) * 512 +
           ((k >> 3) & 1) * 256 + (b & 31) * 8 + (k & 7);
}

#define GLOAD_LDS(gsrc, ldsdst) \
  __builtin_amdgcn_global_load_lds((const __attribute__((address_space(1))) void*)(gsrc), \
                                   (__attribute__((address_space(3))) void*)(ldsdst), 16, 0, 0)

// ---------------- prep kernels ----------------

// W row-major [4096][K] fp32 -> staged bf16 hi/lo:
// [ntile=64][kstep=K/32][ks2][nf=2][kg][col=32][8]   (2048 elems per (ntile,kstep))
__global__ void wstage(const float* __restrict__ src, bf16* __restrict__ hi,
                       bf16* __restrict__ lo, int lk){
    int i = blockIdx.x * 256 + threadIdx.x;
    int K = 1 << lk;
    int n = i >> lk, k = i & (K - 1);
    float v = src[i];
    bf16 h = (bf16)v;
    int off = ((n >> 6) * (K >> 5) + (k >> 5)) * 2048 + ((k >> 4) & 1) * 1024 +
              ((n >> 5) & 1) * 512 + ((k >> 3) & 1) * 256 + (n & 31) * 8 + (k & 7);
    hi[off] = h;
    lo[off] = (bf16)(v - (float)h);
}

// x [B][T][D] fp32 -> staged [T][zoff(b,d)] bf16 hi/lo
__global__ void xstage(const float* __restrict__ x, bf16* __restrict__ hi,
                       bf16* __restrict__ lo){
    int i = blockIdx.x * 256 + threadIdx.x;       // T*B*D = 2^25
    int d = i & 511;
    int b = (i >> 9) & 127;
    int t = i >> 16;
    float v = x[((size_t)b * T_STEPS + t) * DIN + d];
    bf16 h = (bf16)v;
    size_t off = (size_t)t * 65536 + zoff(b, d);
    hi[off] = h;
    lo[off] = (bf16)(v - (float)h);
}

__global__ void bias_kernel(const float* __restrict__ bih1, const float* __restrict__ bhh1,
                            const float* __restrict__ bih2, const float* __restrict__ bhh2,
                            float* __restrict__ bias1, float* __restrict__ bias2){
    int i = blockIdx.x * 256 + threadIdx.x;
    if (i < G4){
        bias1[i] = bih1[i] + bhh1[i];
        bias2[i] = bih2[i] + bhh2[i];
    }
}

// ---------------- per-step GEMM ----------------
// 448 blocks x 256 threads. Block = group g (7 K-shards) x ntile (64 cols).
// Block tile: 128(M) x 64(N) x 512(K); 4 waves each 64x32 via mfma_f32_32x32x16_bf16.
// 3-term split: w_hi*a_hi + w_lo*a_hi + w_hi*a_lo -> fp32 gpart[7][128][4096].
__global__ __launch_bounds__(256)
void gemm_step(const bf16* __restrict__ x_h,  const bf16* __restrict__ x_l,
               const bf16* __restrict__ h1_h, const bf16* __restrict__ h1_l,
               const bf16* __restrict__ h2_h, const bf16* __restrict__ h2_l,
               const bf16* __restrict__ w1x_h, const bf16* __restrict__ w1x_l,
               const bf16* __restrict__ w1h_h, const bf16* __restrict__ w1h_l,
               const bf16* __restrict__ w2i_h, const bf16* __restrict__ w2i_l,
               const bf16* __restrict__ w2h_h, const bf16* __restrict__ w2h_l,
               float* __restrict__ gpart, int t)
{
    int g     = blockIdx.x >> 6;
    int ntile = blockIdx.x & 63;
    if (t == T_STEPS && g < 3) return;   // last round: layer2 only
    if (t == 0 && g >= 3)      return;   // first round: layer1 only
    int p1 = (t - 1) & 1;
    int p2 = t & 1;

    const bf16 *Ah, *Al, *Wh, *Wl;
    int kstep0, wsteps;
    switch (g){
      case 0: Ah = x_h + (size_t)t * 65536; Al = x_l + (size_t)t * 65536;
              Wh = w1x_h; Wl = w1x_l; kstep0 = 0;  wsteps = 16; break;
      case 1: Ah = h1_h + p1 * 131072; Al = h1_l + p1 * 131072;
              Wh = w1h_h; Wl = w1h_l; kstep0 = 0;  wsteps = 32; break;
      case 2: Ah = h1_h + p1 * 131072; Al = h1_l + p1 * 131072;
              Wh = w1h_h; Wl = w1h_l; kstep0 = 16; wsteps = 32; break;
      case 3: Ah = h1_h + p1 * 131072; Al = h1_l + p1 * 131072;
              Wh = w2i_h; Wl = w2i_l; kstep0 = 0;  wsteps = 32; break;
      case 4: Ah = h1_h + p1 * 131072; Al = h1_l + p1 * 131072;
              Wh = w2i_h; Wl = w2i_l; kstep0 = 16; wsteps = 32; break;
      case 5: Ah = h2_h + p2 * 131072; Al = h2_l + p2 * 131072;
              Wh = w2h_h; Wl = w2h_l; kstep0 = 0;  wsteps = 32; break;
      default: Ah = h2_h + p2 * 131072; Al = h2_l + p2 * 131072;
              Wh = w2h_h; Wl = w2h_l; kstep0 = 16; wsteps = 32; break;
    }

    __shared__ __align__(1024) char smem[49152];   // 2 buffers x 24 KB
    int wave = threadIdx.x >> 6;
    int lane = threadIdx.x & 63;
    int wm = wave >> 1, wn = wave & 1;

    // stage one K32 step into buffer buf: A hi 8K | A lo 8K | B hi 4K | B lo 4K
    auto stage = [&](int buf, int s){
        int ks = kstep0 + s;
        const bf16* Ash = Ah + (size_t)ks * 4096;
        const bf16* Asl = Al + (size_t)ks * 4096;
        const bf16* Wsh = Wh + ((size_t)ntile * wsteps + ks) * 2048;
        const bf16* Wsl = Wl + ((size_t)ntile * wsteps + ks) * 2048;
        char* base = smem + buf * 24576;
        #pragma unroll
        for (int c = 0; c < 2; ++c){
            int ii = wave * 2 + c;
            GLOAD_LDS(Ash + ii * 512 + lane * 8, base + ii * 1024);
            GLOAD_LDS(Asl + ii * 512 + lane * 8, base + 8192 + ii * 1024);
        }
        GLOAD_LDS(Wsh + wave * 512 + lane * 8, base + 16384 + wave * 1024);
        GLOAD_LDS(Wsl + wave * 512 + lane * 8, base + 20480 + wave * 1024);
    };

    int laneoff = ((lane >> 5) << 9) + ((lane & 31) << 4);   // bytes within a frag slab
    f32x16 acc0 = {0,0,0,0,0,0,0,0,0,0,0,0,0,0,0,0};
    f32x16 acc1 = {0,0,0,0,0,0,0,0,0,0,0,0,0,0,0,0};

    stage(0, 0);
    __syncthreads();
    for (int s = 0; s < 16; ++s){
        if (s < 15) stage((s + 1) & 1, s + 1);
        const char* b = smem + (s & 1) * 24576;
        #pragma unroll
        for (int k2 = 0; k2 < 2; ++k2){
            bf16x8 a0h = *(const bf16x8*)(b + k2 * 4096 + (wm * 2    ) * 1024 + laneoff);
            bf16x8 a1h = *(const bf16x8*)(b + k2 * 4096 + (wm * 2 + 1) * 1024 + laneoff);
            bf16x8 a0l = *(const bf16x8*)(b + 8192 + k2 * 4096 + (wm * 2    ) * 1024 + laneoff);
            bf16x8 a1l = *(const bf16x8*)(b + 8192 + k2 * 4096 + (wm * 2 + 1) * 1024 + laneoff);
            bf16x8 bh  = *(const bf16x8*)(b + 16384 + k2 * 2048 + wn * 1024 + laneoff);
            bf16x8 bl  = *(const bf16x8*)(b + 20480 + k2 * 2048 + wn * 1024 + laneoff);
            acc0 = __builtin_amdgcn_mfma_f32_32x32x16_bf16(a0h, bh, acc0, 0, 0, 0);
            acc1 = __builtin_amdgcn_mfma_f32_32x32x16_bf16(a1h, bh, acc1, 0, 0, 0);
            acc0 = __builtin_amdgcn_mfma_f32_32x32x16_bf16(a0h, bl, acc0, 0, 0, 0);
            acc1 = __builtin_amdgcn_mfma_f32_32x32x16_bf16(a1h, bl, acc1, 0, 0, 0);
            acc0 = __builtin_amdgcn_mfma_f32_32x32x16_bf16(a0l, bh, acc0, 0, 0, 0);
            acc1 = __builtin_amdgcn_mfma_f32_32x32x16_bf16(a1l, bh, acc1, 0, 0, 0);
        }
        __syncthreads();
    }

    // C/D: col = lane&31, row = (r&3) + 8*(r>>2) + 4*(lane>>5)
    float* gp = gpart + (size_t)g * (BATCH * G4);
    int col = ntile * 64 + wn * 32 + (lane & 31);
    int rbase = 4 * (lane >> 5);
    #pragma unroll
    for (int r = 0; r < 16; ++r){
        int row32 = (r & 3) + 8 * (r >> 2) + rbase;
        gp[(size_t)(wm * 64 + row32) * G4 + col]      = acc0[r];
        gp[(size_t)(wm * 64 + 32 + row32) * G4 + col] = acc1[r];
    }
}

// ---------------- per-step cell update ----------------
__global__ __launch_bounds__(256)
void cell_step(const float* __restrict__ gpart,
               const float* __restrict__ bias1, const float* __restrict__ bias2,
               float* __restrict__ c1, float* __restrict__ c2,
               bf16* __restrict__ h1_h, bf16* __restrict__ h1_l,
               bf16* __restrict__ h2_h, bf16* __restrict__ h2_l,
               float* __restrict__ h2t, int t)
{
    int tid = blockIdx.x * 256 + threadIdx.x;   // 256*256 = 65536 threads
    for (int L = 0; L < 2; ++L){
        if (L == 0 && t == T_STEPS) continue;
        if (L == 1 && t == 0)       continue;
        int s = L ? (t - 1) : t;
        int p = s & 1;
        const float* bias = L ? bias2 : bias1;
        float* c  = L ? c2 : c1;
        bf16* hh = (L ? h2_h : h1_h) + p * 131072;
        bf16* hl = (L ? h2_l : h1_l) + p * 131072;
        int sh0 = L ? 3 : 0;
        int nsh = L ? 4 : 3;
        for (int it = tid; it < BATCH * HID; it += 65536){
            int b = it >> 10;
            int j = it & (HID - 1);
            size_t base = (size_t)b * G4 + j;
            float g4[4];
            #pragma unroll
            for (int q = 0; q < 4; ++q){
                float v = bias[j + q * 1024];
                for (int sh = 0; sh < nsh; ++sh)
                    v += gpart[(size_t)(sh0 + sh) * (BATCH * G4) + base + q * 1024];
                g4[q] = v;
            }
            float iv = sigm(g4[0]), fv = sigm(g4[1]), gv = tanhf(g4[2]), ov = sigm(g4[3]);
            float cn = fv * c[it] + iv * gv;
            c[it] = cn;
            float h = ov * tanhf(cn);
            bf16 hb = (bf16)h;
            int off = zoff(b, j);
            hh[off] = hb;
            hl[off] = (bf16)(h - (float)hb);
            if (L == 1 && s == T_STEPS - 1) h2t[(size_t)j * BATCH + b] = h;
        }
    }
}

// ---------------- output projection (fp32, one-time) ----------------
__global__ __launch_bounds__(128)
void outproj(const float* __restrict__ h2t, const float* __restrict__ wout,
             const float* __restrict__ bout, float* __restrict__ out){
    int o = blockIdx.x;      // 512 blocks
    int b = threadIdx.x;     // 128 threads
    float acc = bout[o];
    const float* wr = wout + (size_t)o * HID;
    for (int k = 0; k < HID; ++k)
        acc += wr[k] * h2t[(size_t)k * BATCH + b];
    out[(size_t)b * DOUT + o] = acc;
}

// ---------------- host launch ----------------
extern "C" void kernel_launch(void* const* d_in, const int* in_sizes, int n_in,
                              void* d_out, int out_size, void* d_ws, size_t ws_size,
                              hipStream_t stream)
{
    const float* x    = (const float*)d_in[0];
    const float* wih1 = (const float*)d_in[1];
    const float* whh1 = (const float*)d_in[2];
    const float* bih1 = (const float*)d_in[3];
    const float* bhh1 = (const float*)d_in[4];
    const float* wih2 = (const float*)d_in[5];
    const float* whh2 = (const float*)d_in[6];
    const float* bih2 = (const float*)d_in[7];
    const float* bhh2 = (const float*)d_in[8];
    const float* wout = (const float*)d_in[9];
    const float* bout = (const float*)d_in[10];
    float* out = (float*)d_out;

    char* p = (char*)d_ws;
    auto alloc = [&](size_t bytes) -> char* {
        char* r = p;
        p += (bytes + 1023) & ~(size_t)1023;
        return r;
    };

    bf16* x_h   = (bf16*)alloc((size_t)T_STEPS * 65536 * 2);
    bf16* x_l   = (bf16*)alloc((size_t)T_STEPS * 65536 * 2);
    bf16* w1x_h = (bf16*)alloc((size_t)G4 * DIN * 2);
    bf16* w1x_l = (bf16*)alloc((size_t)G4 * DIN * 2);
    bf16* w1h_h = (bf16*)alloc((size_t)G4 * HID * 2);
    bf16* w1h_l = (bf16*)alloc((size_t)G4 * HID * 2);
    bf16* w2i_h = (bf16*)alloc((size_t)G4 * HID * 2);
    bf16* w2i_l = (bf16*)alloc((size_t)G4 * HID * 2);
    bf16* w2h_h = (bf16*)alloc((size_t)G4 * HID * 2);
    bf16* w2h_l = (bf16*)alloc((size_t)G4 * HID * 2);
    float* bias1 = (float*)alloc(G4 * 4);
    float* bias2 = (float*)alloc(G4 * 4);
    char* zbase = p;                                   // zeroed block:
    bf16* h1_h = (bf16*)alloc((size_t)2 * 131072 * 2); // staged h parity buffers
    bf16* h1_l = (bf16*)alloc((size_t)2 * 131072 * 2);
    bf16* h2_h = (bf16*)alloc((size_t)2 * 131072 * 2);
    bf16* h2_l = (bf16*)alloc((size_t)2 * 131072 * 2);
    float* c1  = (float*)alloc((size_t)BATCH * HID * 4);
    float* c2  = (float*)alloc((size_t)BATCH * HID * 4);
    size_t zbytes = (size_t)(p - zbase);
    float* gpart = (float*)alloc((size_t)7 * BATCH * G4 * 4);
    float* h2t   = (float*)alloc((size_t)HID * BATCH * 4);
    (void)ws_size; (void)in_sizes; (void)n_in; (void)out_size;

    // prep
    wstage<<<(G4 * DIN) / 256, 256, 0, stream>>>(wih1, w1x_h, w1x_l, 9);
    wstage<<<(G4 * HID) / 256, 256, 0, stream>>>(whh1, w1h_h, w1h_l, 10);
    wstage<<<(G4 * HID) / 256, 256, 0, stream>>>(wih2, w2i_h, w2i_l, 10);
    wstage<<<(G4 * HID) / 256, 256, 0, stream>>>(whh2, w2h_h, w2h_l, 10);
    bias_kernel<<<(G4 + 255) / 256, 256, 0, stream>>>(bih1, bhh1, bih2, bhh2, bias1, bias2);
    xstage<<<(T_STEPS * BATCH * DIN) / 256, 256, 0, stream>>>(x, x_h, x_l);
    hipMemsetAsync(zbase, 0, zbytes, stream);

    // 513 pipelined rounds: round t = layer1(t) + layer2(t-1)
    for (int t = 0; t <= T_STEPS; ++t){
        gemm_step<<<448, 256, 0, stream>>>(x_h, x_l, h1_h, h1_l, h2_h, h2_l,
                                           w1x_h, w1x_l, w1h_h, w1h_l,
                                           w2i_h, w2i_l, w2h_h, w2h_l, gpart, t);
        cell_step<<<256, 256, 0, stream>>>(gpart, bias1, bias2, c1, c2,
                                           h1_h, h1_l, h2_h, h2_l, h2t, t);
    }

    outproj<<<DOUT, BATCH, 0, stream>>>(h2t, wout, bout, out);
}